// Round 6
// baseline (465.758 us; speedup 1.0000x reference)
//
#include <hip/hip_runtime.h>
#include <cstdint>
#include <cstddef>

// ---------------------------------------------------------------------------
// R6: - k_gemm_big upgraded to m97 structure: 128x128 tile, 4 waves/block,
//       BK=64, global_load_lds 16B, XOR-swizzled LDS (was single-wave 64x64,
//       MfmaUtil 13.5%).
//     - k_step: XCD-aware n-tile mapping (blk%8 -> n-group) so each XCD's L2
//       keeps its ~512KB weight slice resident; prefetch depth 3->4.
//     - Q0 = 0.25*(0.5*colsum(w_hp)+bias_p) computed directly (a_h(0)=0.5),
//       so the hp GEMM drops t=0 (M 12288->11264) and shares the oh grid.
//     - pack/transpose kernels consolidated via blockIdx.z.
// ---------------------------------------------------------------------------

typedef _Float16 half8 __attribute__((ext_vector_type(8)));
typedef float floatx4 __attribute__((ext_vector_type(4)));

__device__ __forceinline__ void async_cp16(const void* g, void* l) {
  __builtin_amdgcn_global_load_lds(
      (const __attribute__((address_space(1))) void*)g,
      (__attribute__((address_space(3))) void*)l, 16, 0, 0);
}

__device__ __forceinline__ float sigmoidf_(float x) {
  return 1.f / (1.f + __expf(-x));
}

// ---- transposes for gemm_big B operands: z=0 w_oh->WohT, z=1 w_hp->Whp
__global__ __launch_bounds__(256) void k_trans_all(
    const float* __restrict__ w_oh, const float* __restrict__ w_hp,
    _Float16* __restrict__ WohT, _Float16* __restrict__ Whp) {
  const float* src = blockIdx.z ? w_hp : w_oh;
  _Float16* dst = blockIdx.z ? Whp : WohT;
  __shared__ float tile[64][65];
  const int k0 = blockIdx.y * 64, n0 = blockIdx.x * 64;
  const int tx = threadIdx.x & 63, ty = threadIdx.x >> 6;
#pragma unroll
  for (int j = 0; j < 16; ++j) {
    int kr = j * 4 + ty;
    tile[kr][tx] = src[(size_t)(k0 + kr) * 1024 + n0 + tx];
  }
  __syncthreads();
#pragma unroll
  for (int j = 0; j < 16; ++j) {
    int nr = j * 4 + ty;
    dst[(size_t)(n0 + nr) * 1024 + k0 + tx] = (_Float16)tile[tx][nr];
  }
}

// ---- pack step weights into MFMA B-fragment order.
// chunk (nt,kcG): 4KB = [j 0..3][lane 0..63][8 halves];
// value at n = nt*64 + j*16 + (lane&15), k = kcG*32 + (lane>>4)*8 + u.
// z=0: w_pp->Wrf kOff 0 | z=1: w_cp->Wrf kOff 32 (K=512) | z=2: w_pc->Wcf (N=512)
__global__ __launch_bounds__(256) void k_pack_all(
    const float* __restrict__ w_pp, const float* __restrict__ w_cp,
    const float* __restrict__ w_pc, _Float16* __restrict__ Wrf,
    _Float16* __restrict__ Wcf) {
  const int z = blockIdx.z;
  const float* src;
  _Float16* dst;
  int N, kStride, kOff;
  if (z == 0) {
    src = w_pp; dst = Wrf; N = 1024; kStride = 48; kOff = 0;
  } else if (z == 1) {
    if (blockIdx.y >= 8) return;
    src = w_cp; dst = Wrf; N = 1024; kStride = 48; kOff = 32;
  } else {
    if (blockIdx.x >= 8) return;
    src = w_pc; dst = Wcf; N = 512; kStride = 32; kOff = 0;
  }
  __shared__ float tile[64][65];
  const int k0 = blockIdx.y * 64, n0 = blockIdx.x * 64;
  const int tx = threadIdx.x & 63, ty = threadIdx.x >> 6;
#pragma unroll
  for (int jj = 0; jj < 16; ++jj) {
    int kr = jj * 4 + ty;
    tile[kr][tx] = src[(size_t)(k0 + kr) * N + n0 + tx];
  }
  __syncthreads();
  const int j = threadIdx.x >> 6, lane = threadIdx.x & 63;
  const int r16 = lane & 15, quad = lane >> 4;
#pragma unroll
  for (int c = 0; c < 2; ++c) {
    half8 v;
#pragma unroll
    for (int u = 0; u < 8; ++u)
      v[u] = (_Float16)tile[c * 32 + quad * 8 + u][j * 16 + r16];
    const int kcG = kOff + blockIdx.y * 2 + c;
    *(half8*)(dst + ((size_t)(blockIdx.x * kStride + kcG) * 4 + j) * 512 +
              lane * 8) = v;
  }
}

// ---- Q_0 = 0.25*(0.5*colsum(w_hp) + bias_p), broadcast over batch
__global__ __launch_bounds__(256) void k_q0(
    const float* __restrict__ w_hp, const float* __restrict__ bias_p,
    _Float16* __restrict__ Q) {
  const int n = blockIdx.x * 256 + threadIdx.x;  // 0..1023
  float s = 0.f;
  for (int k = 0; k < 1024; ++k) s += w_hp[(size_t)k * 1024 + n];
  const _Float16 q = (_Float16)(0.25f * (0.5f * s + bias_p[n]));
  for (int b = 0; b < 1024; ++b) Q[(size_t)b * 1024 + n] = q;
}

// ---- prefix scan over t of x (decay 0.75) -> U f16 [11][1024][1024]; inits
__global__ __launch_bounds__(256) void k_prep(
    const float* __restrict__ x, _Float16* __restrict__ U,
    _Float16* __restrict__ AP0, _Float16* __restrict__ AC0,
    float* __restrict__ Pst, float* __restrict__ Cst) {
  const int id = blockIdx.x * 256 + threadIdx.x;  // 0 .. 1M-1
  const int b = id >> 10, i = id & 1023;
  const float* xb = x + (size_t)b * 12 * 1024 + i;
  float g = 0.f;
#pragma unroll
  for (int t = 0; t < 11; ++t) {
    g = xb[t * 1024] + 0.75f * g;
    U[(size_t)t * 1048576 + id] = (_Float16)g;
  }
  AP0[id] = (_Float16)0.5f;
  Pst[id] = 0.f;
  if (i < 512) {
    const int cid = b * 512 + i;
    AC0[cid] = (_Float16)0.5f;
    Cst[cid] = 0.f;
  }
}

// ---- big GEMM, K=1024, m97 structure: 128x128 tile, 4 waves, BK=64.
// wave w stages one 64x64 subtile (w0/w1: A lo/hi, w2/w3: B lo/hi) and
// computes quadrant (wi=w>>1, wj=w&1).
// mode 0: oh -> AH[t]: sigmoid(0.25*acc + beta*bias_h), rows offset +1024
// mode 1: hp -> Q: 0.25*(acc + bias_p)
__global__ __launch_bounds__(256) void k_gemm_big(
    const _Float16* __restrict__ A, const _Float16* __restrict__ B,
    const float* __restrict__ bias, _Float16* __restrict__ dst, int mode) {
  __shared__ __align__(16) _Float16 sA[8192];
  __shared__ __align__(16) _Float16 sB[8192];
  const int lane = threadIdx.x & 63, w = threadIdx.x >> 6;
  const int mBase = blockIdx.y * 128, nBase = blockIdx.x * 128;
  const int r16 = lane & 15, quad = lane >> 4, mrow = lane >> 3;
  const int gsw = ((lane & 7) ^ (mrow & 7)) * 8;
  const floatx4 zero = {0.f, 0.f, 0.f, 0.f};
  floatx4 acc[4][4];
#pragma unroll
  for (int i = 0; i < 4; ++i)
#pragma unroll
    for (int j = 0; j < 4; ++j) acc[i][j] = zero;

  const _Float16* gbase =
      (w < 2 ? A + (size_t)(mBase + (w & 1) * 64 + mrow) * 1024
             : B + (size_t)(nBase + (w & 1) * 64 + mrow) * 1024) +
      gsw;
  _Float16* lbase = (w < 2 ? sA : sB) + (w & 1) * 4096;
  const int wi = w >> 1, wj = w & 1;
  const _Float16* csa = sA + wi * 4096;
  const _Float16* csb = sB + wj * 4096;

  for (int kt = 0; kt < 16; ++kt) {
    const int k0 = kt << 6;
#pragma unroll
    for (int q = 0; q < 8; ++q)
      async_cp16(gbase + (size_t)q * 8192 + k0, lbase + q * 512);
    asm volatile("s_waitcnt vmcnt(0)" ::: "memory");
    __syncthreads();
#pragma unroll
    for (int kk = 0; kk < 2; ++kk) {
      const int sw = ((kk * 4 + quad) ^ (r16 & 7)) * 8;
      half8 af[4], bf[4];
#pragma unroll
      for (int i = 0; i < 4; ++i) af[i] = *(const half8*)&csa[(i * 16 + r16) * 64 + sw];
#pragma unroll
      for (int j = 0; j < 4; ++j) bf[j] = *(const half8*)&csb[(j * 16 + r16) * 64 + sw];
#pragma unroll
      for (int i = 0; i < 4; ++i)
#pragma unroll
        for (int j = 0; j < 4; ++j)
          acc[i][j] =
              __builtin_amdgcn_mfma_f32_16x16x32_f16(af[i], bf[j], acc[i][j], 0, 0, 0);
    }
    __syncthreads();
  }

  const int rowQ = mBase + wi * 64;
  const int colQ = nBase + wj * 64;
  if (mode == 0) {
    const int tm1 = mBase >> 10;  // tile never straddles a t boundary
    const float beta = 1.f - __powf(0.75f, (float)(tm1 + 1));
    _Float16* o = dst + (size_t)(rowQ + 1024) * 1024;
#pragma unroll
    for (int i = 0; i < 4; ++i)
#pragma unroll
      for (int j = 0; j < 4; ++j) {
        const int n = colQ + j * 16 + r16;
#pragma unroll
        for (int r = 0; r < 4; ++r) {
          const int row = i * 16 + quad * 4 + r;
          const float h = 0.25f * acc[i][j][r] + beta * bias[n];
          o[(size_t)row * 1024 + n] = (_Float16)sigmoidf_(h);
        }
      }
  } else {
    _Float16* o = dst + (size_t)rowQ * 1024;
#pragma unroll
    for (int i = 0; i < 4; ++i)
#pragma unroll
      for (int j = 0; j < 4; ++j) {
        const int n = colQ + j * 16 + r16;
#pragma unroll
        for (int r = 0; r < 4; ++r) {
          const int row = i * 16 + quad * 4 + r;
          o[(size_t)row * 1024 + n] = (_Float16)(0.25f * (acc[i][j][r] + bias[n]));
        }
      }
  }
}

// ---- one recurrent step: 4-wave split-K, LDS reduce, frag-packed weights.
// XCD-aware mapping: n-tile == blk (mod 8) so each XCD's L2 keeps its weight
// slice resident across the step's m-tiles.
// blocks 0..511:  P 32m x 64n, K=1536 (12 chunks/wave) over [a_p|a_c]
// blocks 512..767: C 32m x 64n, K=1024 (8 chunks/wave) over a_p
__global__ __launch_bounds__(256, 3) void k_step(
    const _Float16* __restrict__ Qt, const _Float16* __restrict__ APc,
    const _Float16* __restrict__ ACc, _Float16* __restrict__ APn,
    _Float16* __restrict__ ACn, const _Float16* __restrict__ Wrf,
    const _Float16* __restrict__ Wcf, const float* __restrict__ bias_c,
    float* __restrict__ Pst, float* __restrict__ Cst,
    float* __restrict__ out_t) {
  __shared__ float red[4][2][4][4][64];  // 32 KB
  const int lane = threadIdx.x & 63, w = threadIdx.x >> 6;
  const int r16 = lane & 15, quad = lane >> 4;
  const int blk = blockIdx.x;
  const bool isP = blk < 512;
  int mBase, nt;
  if (isP) {
    nt = (blk & 7) | ((blk & 256) ? 8 : 0);  // XCD = blk%8 -> n-group
    mBase = ((blk >> 3) & 31) * 32;
  } else {
    const int b = blk - 512;
    nt = b & 7;
    mBase = (b >> 3) * 32;
  }
  const int nBase = nt * 64;
  const floatx4 zero = {0.f, 0.f, 0.f, 0.f};
  floatx4 acc[2][4];
#pragma unroll
  for (int i = 0; i < 2; ++i)
#pragma unroll
    for (int j = 0; j < 4; ++j) acc[i][j] = zero;

  half8 abuf[4][2], bbuf[4][4];
  auto MM = [&](half8* af, half8* bf) {
#pragma unroll
    for (int i = 0; i < 2; ++i)
#pragma unroll
      for (int j = 0; j < 4; ++j)
        acc[i][j] = __builtin_amdgcn_mfma_f32_16x16x32_f16(af[i], bf[j],
                                                           acc[i][j], 0, 0, 0);
  };

  if (isP) {
    const int kcBase = w * 12;
    auto LD = [&](half8* af, half8* bf, int c) {
      const int kc = kcBase + c;
      const int kg = kc * 32;
      if (kc < 32) {
#pragma unroll
        for (int i = 0; i < 2; ++i)
          af[i] = *(const half8*)(APc + (size_t)(mBase + i * 16 + r16) * 1024 +
                                  kg + quad * 8);
      } else {
#pragma unroll
        for (int i = 0; i < 2; ++i)
          af[i] = *(const half8*)(ACc + (size_t)(mBase + i * 16 + r16) * 512 +
                                  (kg - 1024) + quad * 8);
      }
      const _Float16* wp = Wrf + (size_t)(nt * 48 + kc) * 2048 + lane * 8;
#pragma unroll
      for (int j = 0; j < 4; ++j) bf[j] = *(const half8*)(wp + j * 512);
    };
    LD(abuf[0], bbuf[0], 0);
    LD(abuf[1], bbuf[1], 1);
    LD(abuf[2], bbuf[2], 2);
#pragma unroll
    for (int c = 0; c < 12; ++c) {
      if (c + 3 < 12) LD(abuf[(c + 3) & 3], bbuf[(c + 3) & 3], c + 3);
      MM(abuf[c & 3], bbuf[c & 3]);
    }
  } else {
    const int kcBase = w * 8;
    auto LD = [&](half8* af, half8* bf, int c) {
      const int kc = kcBase + c;
      const int kg = kc * 32;
#pragma unroll
      for (int i = 0; i < 2; ++i)
        af[i] = *(const half8*)(APc + (size_t)(mBase + i * 16 + r16) * 1024 +
                                kg + quad * 8);
      const _Float16* wp = Wcf + (size_t)(nt * 32 + kc) * 2048 + lane * 8;
#pragma unroll
      for (int j = 0; j < 4; ++j) bf[j] = *(const half8*)(wp + j * 512);
    };
    LD(abuf[0], bbuf[0], 0);
    LD(abuf[1], bbuf[1], 1);
    LD(abuf[2], bbuf[2], 2);
#pragma unroll
    for (int c = 0; c < 8; ++c) {
      if (c + 3 < 8) LD(abuf[(c + 3) & 3], bbuf[(c + 3) & 3], c + 3);
      MM(abuf[c & 3], bbuf[c & 3]);
    }
  }

  // cross-wave K reduction
#pragma unroll
  for (int i = 0; i < 2; ++i)
#pragma unroll
    for (int j = 0; j < 4; ++j)
#pragma unroll
      for (int r = 0; r < 4; ++r) red[w][i][j][r][lane] = acc[i][j][r];
  __syncthreads();

  // wave w handles output column group j = w
  if (isP) {
#pragma unroll
    for (int i = 0; i < 2; ++i) {
      const int n = nBase + w * 16 + r16;
#pragma unroll
      for (int r = 0; r < 4; ++r) {
        const float v = red[0][i][w][r][lane] + red[1][i][w][r][lane] +
                        red[2][i][w][r][lane] + red[3][i][w][r][lane];
        const int b = mBase + i * 16 + quad * 4 + r;
        const size_t o = (size_t)b * 1024 + n;
        const float pn = 0.25f * v + (float)Qt[o] + 0.75f * Pst[o];
        Pst[o] = pn;
        const float a = sigmoidf_(pn);
        APn[o] = (_Float16)a;
        if (out_t) out_t[o] = a;
      }
    }
  } else {
#pragma unroll
    for (int i = 0; i < 2; ++i) {
      const int n = nBase + w * 16 + r16;  // 0..511
#pragma unroll
      for (int r = 0; r < 4; ++r) {
        const float v = red[0][i][w][r][lane] + red[1][i][w][r][lane] +
                        red[2][i][w][r][lane] + red[3][i][w][r][lane];
        const int b = mBase + i * 16 + quad * 4 + r;
        const size_t o = (size_t)b * 512 + n;
        const float cn = 0.25f * (v + bias_c[n]) + 0.75f * Cst[o];
        Cst[o] = cn;
        ACn[o] = (_Float16)sigmoidf_(cn);
      }
    }
  }
}

extern "C" void kernel_launch(void* const* d_in, const int* in_sizes, int n_in,
                              void* d_out, int out_size, void* d_ws,
                              size_t ws_size, hipStream_t stream) {
  const float* x      = (const float*)d_in[0];  // [1024,12,1024]
  const float* w_oh   = (const float*)d_in[1];
  const float* w_hp   = (const float*)d_in[2];
  const float* w_pp   = (const float*)d_in[3];  // [k][n]
  const float* w_pc   = (const float*)d_in[4];  // [1024,512]
  const float* w_cp   = (const float*)d_in[5];  // [512,1024]
  const float* bias_h = (const float*)d_in[6];
  const float* bias_p = (const float*)d_in[7];
  const float* bias_c = (const float*)d_in[8];
  float* out = (float*)d_out;

  uint8_t* p = (uint8_t*)d_ws;
  _Float16* Wrf  = (_Float16*)p; p += (size_t)1024 * 1536 * 2;  // frag-packed
  _Float16* Wcf  = (_Float16*)p; p += (size_t)512 * 1024 * 2;   // frag-packed
  _Float16* WohT = (_Float16*)p; p += (size_t)1024 * 1024 * 2;
  _Float16* Whp  = (_Float16*)p; p += (size_t)1024 * 1024 * 2;
  _Float16* U    = (_Float16*)p; p += (size_t)11 * 1048576 * 2;
  _Float16* AH   = (_Float16*)p; p += (size_t)12 * 1048576 * 2;
  _Float16* Q    = (_Float16*)p; p += (size_t)12 * 1048576 * 2;
  _Float16* AP0  = (_Float16*)p; p += (size_t)1048576 * 2;
  _Float16* AP1  = (_Float16*)p; p += (size_t)1048576 * 2;
  _Float16* AC0  = (_Float16*)p; p += (size_t)512 * 1024 * 2;
  _Float16* AC1  = (_Float16*)p; p += (size_t)512 * 1024 * 2;
  float* Pst = (float*)p; p += (size_t)1048576 * 4;
  float* Cst = (float*)p; p += (size_t)512 * 1024 * 4;

  const dim3 blk256(256);
  k_trans_all<<<dim3(16, 16, 2), blk256, 0, stream>>>(w_oh, w_hp, WohT, Whp);
  k_pack_all<<<dim3(16, 16, 3), blk256, 0, stream>>>(w_pp, w_cp, w_pc, Wrf, Wcf);
  k_q0<<<dim3(4), blk256, 0, stream>>>(w_hp, bias_p, Q);
  k_prep<<<4096, blk256, 0, stream>>>(x, U, AP0, AC0, Pst, Cst);
  // hoisted h GEMM -> AH[1..11]  (M=11264, 128-tiles)
  k_gemm_big<<<dim3(8, 88), blk256, 0, stream>>>(U, WohT, bias_h, AH, 0);
  // hoisted hp GEMM: Q_t = 0.25*(a_h_t @ w_hp + bias_p), t=1..11
  k_gemm_big<<<dim3(8, 88), blk256, 0, stream>>>(AH + 1048576, Whp, bias_p,
                                                 Q + 1048576, 1);
  // 12 sequential steps
  for (int t = 0; t < 12; ++t) {
    const _Float16* APc = (t & 1) ? AP1 : AP0;
    _Float16* APn       = (t & 1) ? AP0 : AP1;
    const _Float16* ACc = (t & 1) ? AC1 : AC0;
    _Float16* ACn       = (t & 1) ? AC0 : AC1;
    float* ot = (t >= 8) ? out + (size_t)(t - 8) * 1048576 : (float*)nullptr;
    k_step<<<dim3(768), blk256, 0, stream>>>(Q + (size_t)t * 1048576, APc,
                                             ACc, APn, ACn, Wrf, Wcf, bias_c,
                                             Pst, Cst, ot);
  }
}